// Round 3
// baseline (1581.634 us; speedup 1.0000x reference)
//
#include <hip/hip_runtime.h>

#define FDIM 128

typedef __attribute__((ext_vector_type(8))) short bf16x8;
typedef __attribute__((ext_vector_type(4))) float f32x4;

// ---------------- helpers ----------------

__device__ __forceinline__ unsigned int cvt_bf16(float f) {
    unsigned int u = __float_as_uint(f);
    return (u + 0x7fffu + ((u >> 16) & 1u)) >> 16;   // RNE
}
__device__ __forceinline__ float bf16_lo(unsigned int w) { return __uint_as_float(w << 16); }
__device__ __forceinline__ float bf16_hi(unsigned int w) { return __uint_as_float(w & 0xffff0000u); }

// Packed layout used EVERYWHERE: row of 64 uints; uint u holds bf16 pair
// (feature u [lo], feature u+64 [hi]).  k'-memory ushort order: pos 2u -> feat u,
// pos 2u+1 -> feat u+64.  W^T is stored in the same k' order so GEMM sums match.

// ---------------- CSR build ----------------

__global__ void hist_kernel(const int* __restrict__ tgt, int* __restrict__ count, int ne) {
    int e = blockIdx.x * blockDim.x + threadIdx.x;
    if (e < ne) atomicAdd(&count[tgt[e]], 1);
}

__global__ void dis_kernel(const int* __restrict__ count, float* __restrict__ dis, int n) {
    int i = blockIdx.x * blockDim.x + threadIdx.x;
    if (i < n) {
        float d = (float)(count[i] + 1);   // +1 self-loop
        dis[i] = rsqrtf(d);
    }
}

__global__ void scan_kernel(const int* __restrict__ count, int* __restrict__ rowptr,
                            int* __restrict__ cursor, int n) {
    __shared__ int sums[1024];
    int tid = threadIdx.x;
    int chunk = (n + 1023) / 1024;
    int start = tid * chunk;
    int end   = min(start + chunk, n);
    int s = 0;
    for (int i = start; i < end; i++) s += count[i];
    sums[tid] = s;
    __syncthreads();
    for (int off = 1; off < 1024; off <<= 1) {
        int v = sums[tid];
        int u = (tid >= off) ? sums[tid - off] : 0;
        __syncthreads();
        sums[tid] = v + u;
        __syncthreads();
    }
    int run = (tid == 0) ? 0 : sums[tid - 1];
    for (int i = start; i < end; i++) {
        rowptr[i] = run;
        cursor[i] = run;
        run += count[i];
    }
    if (tid == 1023) rowptr[n] = run;
}

// csr entry: .x = src node, .y = float bits of dis[src]
__global__ void fill_kernel(const int* __restrict__ src, const int* __restrict__ tgt,
                            const float* __restrict__ dis,
                            int* __restrict__ cursor, int2* __restrict__ csr, int ne) {
    int e = blockIdx.x * blockDim.x + threadIdx.x;
    if (e < ne) {
        int t = tgt[e];
        int s = src[e];
        int slot = atomicAdd(&cursor[t], 1);
        csr[slot] = make_int2(s, __float_as_int(dis[s]));
    }
}

// ---------------- input prep: fp32 -> packed bf16 ----------------

__global__ void xprep_kernel(const float* __restrict__ x, unsigned* __restrict__ x16, int total) {
    int i = blockIdx.x * blockDim.x + threadIdx.x;      // total = n*64
    if (i < total) {
        int m = i >> 6, u = i & 63;
        float lo = x[(size_t)m * 128 + u];
        float hi = x[(size_t)m * 128 + u + 64];
        x16[i] = cvt_bf16(lo) | (cvt_bf16(hi) << 16);
    }
}

// Bt16u[n*64 + u] = pack(W[u][n], W[u+64][n])   (W row-major [K=128][N=128])
__global__ void wprep_kernel(const float* __restrict__ W, unsigned* __restrict__ Bt16) {
    int i = blockIdx.x * blockDim.x + threadIdx.x;      // 8192 threads
    if (i < 128 * 64) {
        int nn = i >> 6, u = i & 63;
        float lo = W[(size_t)u * 128 + nn];
        float hi = W[(size_t)(u + 64) * 128 + nn];
        Bt16[i] = cvt_bf16(lo) | (cvt_bf16(hi) << 16);
    }
}

// ---------------- GEMM: Out16[n][64u] = A16[n][64u] @ W (bf16 MFMA) -------------
// block 256 = 4 waves; wave computes a 16x128 strip; no LDS, no barriers.

__global__ __launch_bounds__(256) void gemm_kernel(const unsigned* __restrict__ A16,
                                                   const unsigned* __restrict__ Bt16,
                                                   unsigned* __restrict__ Out16, int n) {
    int tid  = threadIdx.x;
    int wave = tid >> 6, lane = tid & 63;
    int quad = lane >> 4, r16 = lane & 15;
    int m0 = (blockIdx.x * 4 + wave) * 16;
    if (m0 >= n) return;

    f32x4 acc[8] = {};   // 8 n-tiles of 16 cols

    #pragma unroll
    for (int ks = 0; ks < 4; ks++) {
        int m = m0 + r16;
        if (m >= n) m = n - 1;                     // dup-load, store guarded
        // A-frag: lane holds A[m][k'=ks*32+quad*8 .. +7] = uint4 at u = ks*16+quad*4
        uint4 av = *(const uint4*)(A16 + (size_t)m * 64 + ks * 16 + quad * 4);
        bf16x8 af = *(bf16x8*)&av;
        #pragma unroll
        for (int t = 0; t < 8; t++) {
            int ncol = t * 16 + r16;
            uint4 bv = *(const uint4*)(Bt16 + (size_t)ncol * 64 + ks * 16 + quad * 4);
            bf16x8 bf = *(bf16x8*)&bv;
            acc[t] = __builtin_amdgcn_mfma_f32_16x16x32_bf16(af, bf, acc[t], 0, 0, 0);
        }
    }

    // C/D: row = quad*4 + r, col = t*16 + r16.  Pack (col, col+64) = tiles (t, t+4).
    #pragma unroll
    for (int r = 0; r < 4; r++) {
        int row = m0 + quad * 4 + r;
        if (row < n) {
            #pragma unroll
            for (int t = 0; t < 4; t++) {
                unsigned w = cvt_bf16(acc[t][r]) | (cvt_bf16(acc[t + 4][r]) << 16);
                Out16[(size_t)row * 64 + t * 16 + r16] = w;
            }
        }
    }
}

// ---------------- Aggregation: 4 feature passes, wave = 4 nodes x 16 lanes ------
// grid = 4*bpp pass-major blocks; block 256 = 4 waves = 16 nodes.
// pass p gathers 64B/node (uints p*16..p*16+15): slice = n*64B = 3.2MB -> L2-resident.

__global__ __launch_bounds__(256) void agg_kernel(const unsigned* __restrict__ hw16,
                                                  const float* __restrict__ dis,
                                                  const int* __restrict__ rowptr,
                                                  const int2* __restrict__ csr,
                                                  const float* __restrict__ bias,
                                                  unsigned* __restrict__ out16,   // may be null
                                                  float* __restrict__ pool, int n, int bpp) {
    __shared__ float lpool[128];
    int tid = threadIdx.x;
    if (tid < 128) lpool[tid] = 0.f;
    __syncthreads();

    int pass = blockIdx.x / bpp;
    int blk  = blockIdx.x % bpp;
    int wave = tid >> 6, lane = tid & 63;
    int g = lane >> 4, sub = lane & 15;
    int node = (blk * 4 + wave) * 4 + g;
    int u = pass * 16 + sub;

    float r0 = 0.f, r1 = 0.f;
    bool valid = node < n;
    int beg = 0, deg = 0;
    float di = 0.f, a0 = 0.f, a1 = 0.f;
    if (valid) {
        di = dis[node];
        unsigned self = hw16[(unsigned)node * 64u + u];
        a0 = di * bf16_lo(self);
        a1 = di * bf16_hi(self);
        beg = rowptr[node];
        deg = rowptr[node + 1] - beg;
    }
    // wave-uniform round count
    int maxdeg = max(deg, __shfl_xor(deg, 16));
    maxdeg = max(maxdeg, __shfl_xor(maxdeg, 32));

    for (int base = 0; base < maxdeg; base += 16) {
        int idx = base + sub;
        int ssrc = 0; float sval = 0.f;
        if (idx < deg) {
            int2 e = csr[beg + idx];
            ssrc = e.x;
            sval = __int_as_float(e.y);
        }
        #pragma unroll
        for (int j0 = 0; j0 < 16; j0 += 8) {
            unsigned gv[8]; float vv[8];
            #pragma unroll
            for (int q = 0; q < 8; q++) {
                int sl = g * 16 + j0 + q;
                int s  = __shfl(ssrc, sl);
                vv[q]  = __shfl(sval, sl);        // 0 past degree -> contributes 0
                gv[q]  = hw16[(unsigned)s * 64u + u];
            }
            #pragma unroll
            for (int q = 0; q < 8; q++) {
                a0 += vv[q] * bf16_lo(gv[q]);
                a1 += vv[q] * bf16_hi(gv[q]);
            }
        }
    }

    if (valid) {
        r0 = fmaxf(di * a0 + bias[u], 0.f);
        r1 = fmaxf(di * a1 + bias[u + 64], 0.f);
        if (out16) {
            out16[(unsigned)node * 64u + u] = cvt_bf16(r0) | (cvt_bf16(r1) << 16);
        }
    }
    // pool: reduce the 4 node-groups (same feature u across g)
    r0 += __shfl_xor(r0, 16);  r0 += __shfl_xor(r0, 32);
    r1 += __shfl_xor(r1, 16);  r1 += __shfl_xor(r1, 32);
    if (g == 0) {
        atomicAdd(&lpool[u], r0);
        atomicAdd(&lpool[u + 64], r1);
    }
    __syncthreads();
    if (tid < 128) atomicAdd(&pool[tid], lpool[tid]);
}

// ---------------- MLP head (single block) ----------------

__global__ __launch_bounds__(128) void mlp_kernel(const float* __restrict__ pool,
                                                  const float* __restrict__ fw1, const float* __restrict__ fb1,
                                                  const float* __restrict__ fw2, const float* __restrict__ fb2,
                                                  const float* __restrict__ fw3, const float* __restrict__ fb3,
                                                  float* __restrict__ out) {
    __shared__ float h0[384];
    __shared__ float h1[128];
    __shared__ float h2[64];
    int tid = threadIdx.x;
    for (int i = tid; i < 384; i += 128) h0[i] = pool[i];
    __syncthreads();
    {
        float s = fb1[tid];
        for (int k = 0; k < 384; k++) s += h0[k] * fw1[k * 128 + tid];
        h1[tid] = fmaxf(s, 0.f);
    }
    __syncthreads();
    if (tid < 64) {
        float s = fb2[tid];
        for (int k = 0; k < 128; k++) s += h1[k] * fw2[k * 64 + tid];
        h2[tid] = fmaxf(s, 0.f);
    }
    __syncthreads();
    if (tid < 10) {
        float s = fb3[tid];
        for (int k = 0; k < 64; k++) s += h2[k] * fw3[k * 10 + tid];
        out[tid] = s;
    }
}

// ---------------- launch ----------------

extern "C" void kernel_launch(void* const* d_in, const int* in_sizes, int n_in,
                              void* d_out, int out_size, void* d_ws, size_t ws_size,
                              hipStream_t stream) {
    const float* x   = (const float*)d_in[0];
    const int*   ei  = (const int*)d_in[1];
    const float* W1  = (const float*)d_in[2];
    const float* b1  = (const float*)d_in[3];
    const float* W2  = (const float*)d_in[4];
    const float* b2  = (const float*)d_in[5];
    const float* W3  = (const float*)d_in[6];
    const float* b3  = (const float*)d_in[7];
    const float* fw1 = (const float*)d_in[8];
    const float* fb1 = (const float*)d_in[9];
    const float* fw2 = (const float*)d_in[10];
    const float* fb2 = (const float*)d_in[11];
    const float* fw3 = (const float*)d_in[12];
    const float* fb3 = (const float*)d_in[13];
    float* out = (float*)d_out;

    const int n  = in_sizes[0] / FDIM;   // 50000
    const int ne = in_sizes[1] / 2;      // 600000
    const int* src = ei;
    const int* tgt = ei + ne;

    // workspace layout (16B aligned)
    char* ws = (char*)d_ws;
    size_t packBytes = (size_t)n * 64 * sizeof(unsigned);   // 12.8 MB
    unsigned* x16  = (unsigned*)ws;  ws += packBytes;
    unsigned* hw16 = (unsigned*)ws;  ws += packBytes;
    unsigned* A2   = (unsigned*)ws;  ws += packBytes;       // x1 packed
    unsigned* A3   = (unsigned*)ws;  ws += packBytes;       // x2 packed
    unsigned* B1t  = (unsigned*)ws;  ws += 128 * 64 * 4;
    unsigned* B2t  = (unsigned*)ws;  ws += 128 * 64 * 4;
    unsigned* B3t  = (unsigned*)ws;  ws += 128 * 64 * 4;
    float* dis  = (float*)ws;        ws += (size_t)n * 4;
    int* count  = (int*)ws;          ws += (size_t)n * 4;
    int* rowptr = (int*)ws;          ws += ((size_t)(n + 4) * 4 / 16) * 16;
    int* cursor = (int*)ws;          ws += (size_t)n * 4;
    int2* csr   = (int2*)ws;         ws += (size_t)ne * 8;
    float* pool = (float*)ws;        ws += 384 * 4;

    hipMemsetAsync(count, 0, (size_t)n * 4, stream);
    hipMemsetAsync(pool, 0, 384 * 4, stream);

    // prep
    xprep_kernel<<<(n * 64 + 255) / 256, 256, 0, stream>>>(x, x16, n * 64);
    wprep_kernel<<<32, 256, 0, stream>>>(W1, B1t);
    wprep_kernel<<<32, 256, 0, stream>>>(W2, B2t);
    wprep_kernel<<<32, 256, 0, stream>>>(W3, B3t);

    // CSR build
    hist_kernel<<<(ne + 255) / 256, 256, 0, stream>>>(tgt, count, ne);
    dis_kernel<<<(n + 255) / 256, 256, 0, stream>>>(count, dis, n);
    scan_kernel<<<1, 1024, 0, stream>>>(count, rowptr, cursor, n);
    fill_kernel<<<(ne + 255) / 256, 256, 0, stream>>>(src, tgt, dis, cursor, csr, ne);

    int gemmGrid = (n + 63) / 64;              // 64 rows per block
    int bpp      = (n + 15) / 16;              // blocks per pass (16 nodes/block)
    int aggGrid  = 4 * bpp;

    gemm_kernel<<<gemmGrid, 256, 0, stream>>>(x16, B1t, hw16, n);
    agg_kernel<<<aggGrid, 256, 0, stream>>>(hw16, dis, rowptr, csr, b1, A2, pool + 0, n, bpp);

    gemm_kernel<<<gemmGrid, 256, 0, stream>>>(A2, B2t, hw16, n);
    agg_kernel<<<aggGrid, 256, 0, stream>>>(hw16, dis, rowptr, csr, b2, A3, pool + 128, n, bpp);

    gemm_kernel<<<gemmGrid, 256, 0, stream>>>(A3, B3t, hw16, n);
    agg_kernel<<<aggGrid, 256, 0, stream>>>(hw16, dis, rowptr, csr, b3, (unsigned*)nullptr, pool + 256, n, bpp);

    mlp_kernel<<<1, 128, 0, stream>>>(pool, fw1, fb1, fw2, fb2, fw3, fb3, out);
}

// Round 4
// 744.956 us; speedup vs baseline: 2.1231x; 2.1231x over previous
//
#include <hip/hip_runtime.h>

#define FDIM 128

typedef __attribute__((ext_vector_type(8))) short bf16x8;
typedef __attribute__((ext_vector_type(4))) float f32x4;

// ---------------- helpers ----------------

__device__ __forceinline__ unsigned int cvt_bf16(float f) {
    unsigned int u = __float_as_uint(f);
    return (u + 0x7fffu + ((u >> 16) & 1u)) >> 16;   // RNE
}
__device__ __forceinline__ float bf16_lo(unsigned int w) { return __uint_as_float(w << 16); }
__device__ __forceinline__ float bf16_hi(unsigned int w) { return __uint_as_float(w & 0xffff0000u); }

// Packed layout EVERYWHERE: row of 64 uints; uint u = bf16 pair (feat u, feat u+64).

// ---------------- CSR build ----------------

__global__ void hist_kernel(const int* __restrict__ tgt, int* __restrict__ count, int ne) {
    int e = blockIdx.x * blockDim.x + threadIdx.x;
    if (e < ne) atomicAdd(&count[tgt[e]], 1);
}

// scan + dis + pool-zero fused (single block)
__global__ void scan_kernel(const int* __restrict__ count, int* __restrict__ rowptr,
                            int* __restrict__ cursor, float* __restrict__ dis,
                            float* __restrict__ pool, int n) {
    __shared__ int sums[1024];
    int tid = threadIdx.x;
    if (tid < 384) pool[tid] = 0.f;
    int chunk = (n + 1023) / 1024;
    int start = tid * chunk;
    int end   = min(start + chunk, n);
    int s = 0;
    for (int i = start; i < end; i++) {
        int c = count[i];
        s += c;
        dis[i] = rsqrtf((float)(c + 1));   // +1 self-loop
    }
    sums[tid] = s;
    __syncthreads();
    for (int off = 1; off < 1024; off <<= 1) {
        int v = sums[tid];
        int u = (tid >= off) ? sums[tid - off] : 0;
        __syncthreads();
        sums[tid] = v + u;
        __syncthreads();
    }
    int run = (tid == 0) ? 0 : sums[tid - 1];
    for (int i = start; i < end; i++) {
        rowptr[i] = run;
        cursor[i] = run;
        run += count[i];
    }
    if (tid == 1023) rowptr[n] = run;
}

// csr entry: .x = src node, .y = float bits of dis[src]
__global__ void fill_kernel(const int* __restrict__ src, const int* __restrict__ tgt,
                            const float* __restrict__ dis,
                            int* __restrict__ cursor, int2* __restrict__ csr, int ne) {
    int e = blockIdx.x * blockDim.x + threadIdx.x;
    if (e < ne) {
        int t = tgt[e];
        int s = src[e];
        int slot = atomicAdd(&cursor[t], 1);
        csr[slot] = make_int2(s, __float_as_int(dis[s]));
    }
}

// ---------------- prep: fp32 -> packed bf16 ----------------

__global__ void xprep_kernel(const float* __restrict__ x, unsigned* __restrict__ x16, int total) {
    int i = blockIdx.x * blockDim.x + threadIdx.x;      // total = n*64
    if (i < total) {
        int m = i >> 6, u = i & 63;
        float lo = x[(size_t)m * 128 + u];
        float hi = x[(size_t)m * 128 + u + 64];
        x16[i] = cvt_bf16(lo) | (cvt_bf16(hi) << 16);
    }
}

// all three weights in one launch: Bt[n*64+u] = pack(W[u][n], W[u+64][n])
__global__ void wprep_kernel(const float* __restrict__ W1, const float* __restrict__ W2,
                             const float* __restrict__ W3,
                             unsigned* __restrict__ B1, unsigned* __restrict__ B2,
                             unsigned* __restrict__ B3) {
    int i = blockIdx.x * blockDim.x + threadIdx.x;      // 3*8192
    if (i < 3 * 8192) {
        int w = i >> 13;
        int j = i & 8191;
        const float* W = (w == 0) ? W1 : (w == 1) ? W2 : W3;
        unsigned* B    = (w == 0) ? B1 : (w == 1) ? B2 : B3;
        int nn = j >> 6, u = j & 63;
        float lo = W[(size_t)u * 128 + nn];
        float hi = W[(size_t)(u + 64) * 128 + nn];
        B[j] = cvt_bf16(lo) | (cvt_bf16(hi) << 16);
    }
}

// ---------------- GEMM: Out16[n][64u] = A16 @ W (bf16 MFMA, no LDS) -------------

__global__ __launch_bounds__(256) void gemm_kernel(const unsigned* __restrict__ A16,
                                                   const unsigned* __restrict__ Bt16,
                                                   unsigned* __restrict__ Out16, int n) {
    int tid  = threadIdx.x;
    int wave = tid >> 6, lane = tid & 63;
    int quad = lane >> 4, r16 = lane & 15;
    int m0 = (blockIdx.x * 4 + wave) * 16;
    if (m0 >= n) return;

    f32x4 acc[8] = {};

    #pragma unroll
    for (int ks = 0; ks < 4; ks++) {
        int m = m0 + r16;
        if (m >= n) m = n - 1;
        uint4 av = *(const uint4*)(A16 + (size_t)m * 64 + ks * 16 + quad * 4);
        bf16x8 af = *(bf16x8*)&av;
        #pragma unroll
        for (int t = 0; t < 8; t++) {
            int ncol = t * 16 + r16;
            uint4 bv = *(const uint4*)(Bt16 + (size_t)ncol * 64 + ks * 16 + quad * 4);
            bf16x8 bf = *(bf16x8*)&bv;
            acc[t] = __builtin_amdgcn_mfma_f32_16x16x32_bf16(af, bf, acc[t], 0, 0, 0);
        }
    }

    #pragma unroll
    for (int r = 0; r < 4; r++) {
        int row = m0 + quad * 4 + r;
        if (row < n) {
            #pragma unroll
            for (int t = 0; t < 4; t++) {
                unsigned w = cvt_bf16(acc[t][r]) | (cvt_bf16(acc[t + 4][r]) << 16);
                Out16[(size_t)row * 64 + t * 16 + r16] = w;
            }
        }
    }
}

// ---------------- Aggregation: node-pair per wave, full-row gathers, dbuf -------
// block 512 = 8 waves = 16 nodes; contiguous CSR range [rowptr[A], rowptr[A+2])
// with per-slot A/B predication; double-buffered 8-gather pipeline (16 in flight).

#define AGG_ISSUE(buf, jj)                                            \
    { _Pragma("unroll") for (int q = 0; q < 8; q++) {                 \
        int s = __shfl(sreg, (jj) * 8 + q);                           \
        buf[q] = hw16[(unsigned)s * 64u + lane]; } }

#define AGG_CONSUME(buf, jj)                                          \
    { _Pragma("unroll") for (int q = 0; q < 8; q++) {                 \
        float fA = __shfl(vAr, (jj) * 8 + q);                         \
        float fB = __shfl(vBr, (jj) * 8 + q);                         \
        float lo = bf16_lo(buf[q]), hi = bf16_hi(buf[q]);             \
        a0A += fA * lo; a1A += fA * hi;                               \
        a0B += fB * lo; a1B += fB * hi; } }

__global__ __launch_bounds__(512) void agg_kernel(const unsigned* __restrict__ hw16,
                                                  const float* __restrict__ dis,
                                                  const int* __restrict__ rowptr,
                                                  const int2* __restrict__ csr,
                                                  const float* __restrict__ bias,
                                                  unsigned* __restrict__ out16,   // may be null
                                                  float* __restrict__ pool, int n) {
    __shared__ float lpool[128];
    int tid = threadIdx.x;
    if (tid < 128) lpool[tid] = 0.f;
    __syncthreads();

    int wave = tid >> 6, lane = tid & 63;
    int nodeA = blockIdx.x * 16 + wave * 2;
    int nodeB = nodeA + 1;
    bool okA = nodeA < n, okB = nodeB < n;

    float diA = okA ? dis[nodeA] : 0.f;
    float diB = okB ? dis[nodeB] : 0.f;
    float a0A = 0.f, a1A = 0.f, a0B = 0.f, a1B = 0.f;
    if (okA) { unsigned s = hw16[(unsigned)nodeA * 64u + lane]; a0A = diA * bf16_lo(s); a1A = diA * bf16_hi(s); }
    if (okB) { unsigned s = hw16[(unsigned)nodeB * 64u + lane]; a0B = diB * bf16_lo(s); a1B = diB * bf16_hi(s); }

    int beg = okA ? rowptr[nodeA] : 0;
    int mid = okA ? rowptr[nodeA + 1] : 0;
    int end = okB ? rowptr[nodeB + 1] : mid;

    for (int b = beg; b < end; b += 64) {
        int m = min(64, end - b);
        int sreg = 0; float vAr = 0.f, vBr = 0.f;
        if (lane < m) {
            int2 e = csr[b + lane];
            sreg = e.x;
            float v = __int_as_float(e.y);
            bool isA = (b + lane) < mid;
            vAr = isA ? v : 0.f;
            vBr = isA ? 0.f : v;
        }
        int nb = (m + 7) >> 3;
        unsigned gv0[8], gv1[8];
        AGG_ISSUE(gv0, 0)
        int j = 0;
        while (true) {
            if (j + 1 < nb) AGG_ISSUE(gv1, j + 1)
            AGG_CONSUME(gv0, j)
            j++;
            if (j >= nb) break;
            if (j + 1 < nb) AGG_ISSUE(gv0, j + 1)
            AGG_CONSUME(gv1, j)
            j++;
            if (j >= nb) break;
        }
    }

    float r0A = 0.f, r1A = 0.f, r0B = 0.f, r1B = 0.f;
    if (okA) {
        r0A = fmaxf(diA * a0A + bias[lane], 0.f);
        r1A = fmaxf(diA * a1A + bias[lane + 64], 0.f);
        if (out16) out16[(unsigned)nodeA * 64u + lane] = cvt_bf16(r0A) | (cvt_bf16(r1A) << 16);
    }
    if (okB) {
        r0B = fmaxf(diB * a0B + bias[lane], 0.f);
        r1B = fmaxf(diB * a1B + bias[lane + 64], 0.f);
        if (out16) out16[(unsigned)nodeB * 64u + lane] = cvt_bf16(r0B) | (cvt_bf16(r1B) << 16);
    }
    atomicAdd(&lpool[lane],      r0A + r0B);
    atomicAdd(&lpool[lane + 64], r1A + r1B);
    __syncthreads();
    if (tid < 128) atomicAdd(&pool[tid], lpool[tid]);
}

// ---------------- MLP head (single block) ----------------

__global__ __launch_bounds__(128) void mlp_kernel(const float* __restrict__ pool,
                                                  const float* __restrict__ fw1, const float* __restrict__ fb1,
                                                  const float* __restrict__ fw2, const float* __restrict__ fb2,
                                                  const float* __restrict__ fw3, const float* __restrict__ fb3,
                                                  float* __restrict__ out) {
    __shared__ float h0[384];
    __shared__ float h1[128];
    __shared__ float h2[64];
    int tid = threadIdx.x;
    for (int i = tid; i < 384; i += 128) h0[i] = pool[i];
    __syncthreads();
    {
        float s = fb1[tid];
        for (int k = 0; k < 384; k++) s += h0[k] * fw1[k * 128 + tid];
        h1[tid] = fmaxf(s, 0.f);
    }
    __syncthreads();
    if (tid < 64) {
        float s = fb2[tid];
        for (int k = 0; k < 128; k++) s += h1[k] * fw2[k * 64 + tid];
        h2[tid] = fmaxf(s, 0.f);
    }
    __syncthreads();
    if (tid < 10) {
        float s = fb3[tid];
        for (int k = 0; k < 64; k++) s += h2[k] * fw3[k * 10 + tid];
        out[tid] = s;
    }
}

// ---------------- launch ----------------

extern "C" void kernel_launch(void* const* d_in, const int* in_sizes, int n_in,
                              void* d_out, int out_size, void* d_ws, size_t ws_size,
                              hipStream_t stream) {
    const float* x   = (const float*)d_in[0];
    const int*   ei  = (const int*)d_in[1];
    const float* W1  = (const float*)d_in[2];
    const float* b1  = (const float*)d_in[3];
    const float* W2  = (const float*)d_in[4];
    const float* b2  = (const float*)d_in[5];
    const float* W3  = (const float*)d_in[6];
    const float* b3  = (const float*)d_in[7];
    const float* fw1 = (const float*)d_in[8];
    const float* fb1 = (const float*)d_in[9];
    const float* fw2 = (const float*)d_in[10];
    const float* fb2 = (const float*)d_in[11];
    const float* fw3 = (const float*)d_in[12];
    const float* fb3 = (const float*)d_in[13];
    float* out = (float*)d_out;

    const int n  = in_sizes[0] / FDIM;   // 50000
    const int ne = in_sizes[1] / 2;      // 600000
    const int* src = ei;
    const int* tgt = ei + ne;

    char* ws = (char*)d_ws;
    size_t packBytes = (size_t)n * 64 * sizeof(unsigned);   // 12.8 MB
    unsigned* x16  = (unsigned*)ws;  ws += packBytes;
    unsigned* hw16 = (unsigned*)ws;  ws += packBytes;
    unsigned* A2   = (unsigned*)ws;  ws += packBytes;
    unsigned* A3   = (unsigned*)ws;  ws += packBytes;
    unsigned* B1t  = (unsigned*)ws;  ws += 128 * 64 * 4;
    unsigned* B2t  = (unsigned*)ws;  ws += 128 * 64 * 4;
    unsigned* B3t  = (unsigned*)ws;  ws += 128 * 64 * 4;
    float* dis  = (float*)ws;        ws += (size_t)n * 4;
    int* count  = (int*)ws;          ws += (size_t)n * 4;
    int* rowptr = (int*)ws;          ws += ((size_t)(n + 4) * 4 / 16) * 16;
    int* cursor = (int*)ws;          ws += (size_t)n * 4;
    int2* csr   = (int2*)ws;         ws += (size_t)ne * 8;
    float* pool = (float*)ws;        ws += 384 * 4;

    hipMemsetAsync(count, 0, (size_t)n * 4, stream);

    xprep_kernel<<<(n * 64 + 255) / 256, 256, 0, stream>>>(x, x16, n * 64);
    wprep_kernel<<<(3 * 8192 + 255) / 256, 256, 0, stream>>>(W1, W2, W3, B1t, B2t, B3t);

    hist_kernel<<<(ne + 255) / 256, 256, 0, stream>>>(tgt, count, ne);
    scan_kernel<<<1, 1024, 0, stream>>>(count, rowptr, cursor, dis, pool, n);
    fill_kernel<<<(ne + 255) / 256, 256, 0, stream>>>(src, tgt, dis, cursor, csr, ne);

    int gemmGrid = (n + 63) / 64;
    int aggGrid  = (n + 15) / 16;

    gemm_kernel<<<gemmGrid, 256, 0, stream>>>(x16, B1t, hw16, n);
    agg_kernel<<<aggGrid, 512, 0, stream>>>(hw16, dis, rowptr, csr, b1, A2, pool + 0, n);

    gemm_kernel<<<gemmGrid, 256, 0, stream>>>(A2, B2t, hw16, n);
    agg_kernel<<<aggGrid, 512, 0, stream>>>(hw16, dis, rowptr, csr, b2, A3, pool + 128, n);

    gemm_kernel<<<gemmGrid, 256, 0, stream>>>(A3, B3t, hw16, n);
    agg_kernel<<<aggGrid, 512, 0, stream>>>(hw16, dis, rowptr, csr, b3, (unsigned*)nullptr, pool + 256, n);

    mlp_kernel<<<1, 128, 0, stream>>>(pool, fw1, fb1, fw2, fb2, fw3, fb3, out);
}

// Round 5
// 593.484 us; speedup vs baseline: 2.6650x; 1.2552x over previous
//
#include <hip/hip_runtime.h>

#define FDIM 128

typedef __attribute__((ext_vector_type(8))) short bf16x8;
typedef __attribute__((ext_vector_type(4))) float f32x4;

// ---------------- helpers ----------------

__device__ __forceinline__ unsigned int cvt_bf16(float f) {
    unsigned int u = __float_as_uint(f);
    return (u + 0x7fffu + ((u >> 16) & 1u)) >> 16;   // RNE
}
__device__ __forceinline__ float bf16_lo(unsigned int w) { return __uint_as_float(w << 16); }
__device__ __forceinline__ float bf16_hi(unsigned int w) { return __uint_as_float(w & 0xffff0000u); }

// Packed layout EVERYWHERE: row of 64 uints; uint u = bf16 pair (feat u, feat u+64).

// ---------------- CSR build ----------------

__global__ void hist_kernel(const int* __restrict__ tgt, int* __restrict__ count, int ne) {
    int e = blockIdx.x * blockDim.x + threadIdx.x;
    if (e < ne) atomicAdd(&count[tgt[e]], 1);
}

// ---- 3-phase parallel scan: 2048 elems/block ----
// phase 1: per-thread sum of 8 elems, LDS scan, emit thread-prefix + block-sum; dis fused
__global__ __launch_bounds__(256) void scan1_kernel(const int* __restrict__ count,
                                                    float* __restrict__ dis,
                                                    int* __restrict__ tpre,
                                                    int* __restrict__ bsum, int n) {
    __shared__ int sm[256];
    int tid = threadIdx.x, blk = blockIdx.x;
    int base = blk * 2048 + tid * 8;
    int s = 0;
    #pragma unroll
    for (int q = 0; q < 8; q++) {
        int i = base + q;
        if (i < n) {
            int c = count[i];
            s += c;
            dis[i] = rsqrtf((float)(c + 1));   // +1 self-loop
        }
    }
    sm[tid] = s;
    __syncthreads();
    for (int off = 1; off < 256; off <<= 1) {
        int v = sm[tid];
        int u = (tid >= off) ? sm[tid - off] : 0;
        __syncthreads();
        sm[tid] = v + u;
        __syncthreads();
    }
    tpre[blk * 256 + tid] = (tid == 0) ? 0 : sm[tid - 1];
    if (tid == 255) bsum[blk] = sm[255];
}

// phase 2: single tiny block scans block sums (nb <= 1024); pool zero fused
__global__ __launch_bounds__(1024) void scan2_kernel(const int* __restrict__ bsum,
                                                     int* __restrict__ bpre,
                                                     int* __restrict__ rowptr,
                                                     float* __restrict__ pool,
                                                     int n, int nb) {
    __shared__ int sm[1024];
    int tid = threadIdx.x;
    if (tid < 384) pool[tid] = 0.f;
    sm[tid] = (tid < nb) ? bsum[tid] : 0;
    __syncthreads();
    for (int off = 1; off < 1024; off <<= 1) {
        int v = sm[tid];
        int u = (tid >= off) ? sm[tid - off] : 0;
        __syncthreads();
        sm[tid] = v + u;
        __syncthreads();
    }
    if (tid < nb) bpre[tid] = (tid == 0) ? 0 : sm[tid - 1];
    if (tid == nb - 1) rowptr[n] = sm[tid];
}

// phase 3: write rowptr + cursor
__global__ __launch_bounds__(256) void scan3_kernel(const int* __restrict__ count,
                                                    const int* __restrict__ tpre,
                                                    const int* __restrict__ bpre,
                                                    int* __restrict__ rowptr,
                                                    int* __restrict__ cursor, int n) {
    int tid = threadIdx.x, blk = blockIdx.x;
    int run = bpre[blk] + tpre[blk * 256 + tid];
    int base = blk * 2048 + tid * 8;
    #pragma unroll
    for (int q = 0; q < 8; q++) {
        int i = base + q;
        if (i < n) {
            rowptr[i] = run;
            cursor[i] = run;
            run += count[i];
        }
    }
}

// csr entry: .x = src node, .y = float bits of dis[src]
__global__ void fill_kernel(const int* __restrict__ src, const int* __restrict__ tgt,
                            const float* __restrict__ dis,
                            int* __restrict__ cursor, int2* __restrict__ csr, int ne) {
    int e = blockIdx.x * blockDim.x + threadIdx.x;
    if (e < ne) {
        int t = tgt[e];
        int s = src[e];
        int slot = atomicAdd(&cursor[t], 1);
        csr[slot] = make_int2(s, __float_as_int(dis[s]));
    }
}

// ---------------- prep: fp32 -> packed bf16 (+ count zero) ----------------

__global__ void xprep_kernel(const float* __restrict__ x, unsigned* __restrict__ x16,
                             int* __restrict__ count, int n, int total) {
    int i = blockIdx.x * blockDim.x + threadIdx.x;      // total = n*64
    if (i < total) {
        int m = i >> 6, u = i & 63;
        float lo = x[(size_t)m * 128 + u];
        float hi = x[(size_t)m * 128 + u + 64];
        x16[i] = cvt_bf16(lo) | (cvt_bf16(hi) << 16);
        if (i < n) count[i] = 0;
    }
}

// all three weights in one launch: Bt[n*64+u] = pack(W[u][n], W[u+64][n])
__global__ void wprep_kernel(const float* __restrict__ W1, const float* __restrict__ W2,
                             const float* __restrict__ W3,
                             unsigned* __restrict__ B1, unsigned* __restrict__ B2,
                             unsigned* __restrict__ B3) {
    int i = blockIdx.x * blockDim.x + threadIdx.x;      // 3*8192
    if (i < 3 * 8192) {
        int w = i >> 13;
        int j = i & 8191;
        const float* W = (w == 0) ? W1 : (w == 1) ? W2 : W3;
        unsigned* B    = (w == 0) ? B1 : (w == 1) ? B2 : B3;
        int nn = j >> 6, u = j & 63;
        float lo = W[(size_t)u * 128 + nn];
        float hi = W[(size_t)(u + 64) * 128 + nn];
        B[j] = cvt_bf16(lo) | (cvt_bf16(hi) << 16);
    }
}

// ---------------- GEMM: Out16[n][64u] = A16 @ W (bf16 MFMA, no LDS) -------------

__global__ __launch_bounds__(256) void gemm_kernel(const unsigned* __restrict__ A16,
                                                   const unsigned* __restrict__ Bt16,
                                                   unsigned* __restrict__ Out16, int n) {
    int tid  = threadIdx.x;
    int wave = tid >> 6, lane = tid & 63;
    int quad = lane >> 4, r16 = lane & 15;
    int m0 = (blockIdx.x * 4 + wave) * 16;
    if (m0 >= n) return;

    f32x4 acc[8] = {};

    #pragma unroll
    for (int ks = 0; ks < 4; ks++) {
        int m = m0 + r16;
        if (m >= n) m = n - 1;
        uint4 av = *(const uint4*)(A16 + (size_t)m * 64 + ks * 16 + quad * 4);
        bf16x8 af = *(bf16x8*)&av;
        #pragma unroll
        for (int t = 0; t < 8; t++) {
            int ncol = t * 16 + r16;
            uint4 bv = *(const uint4*)(Bt16 + (size_t)ncol * 64 + ks * 16 + quad * 4);
            bf16x8 bf = *(bf16x8*)&bv;
            acc[t] = __builtin_amdgcn_mfma_f32_16x16x32_bf16(af, bf, acc[t], 0, 0, 0);
        }
    }

    #pragma unroll
    for (int r = 0; r < 4; r++) {
        int row = m0 + quad * 4 + r;
        if (row < n) {
            #pragma unroll
            for (int t = 0; t < 4; t++) {
                unsigned w = cvt_bf16(acc[t][r]) | (cvt_bf16(acc[t + 4][r]) << 16);
                Out16[(size_t)row * 64 + t * 16 + r16] = w;
            }
        }
    }
}

// ---------------- Aggregation: node-pair per wave, full-row gathers, dbuf -------

#define AGG_ISSUE(buf, jj)                                            \
    { _Pragma("unroll") for (int q = 0; q < 8; q++) {                 \
        int s = __shfl(sreg, (jj) * 8 + q);                           \
        buf[q] = hw16[(unsigned)s * 64u + lane]; } }

#define AGG_CONSUME(buf, jj)                                          \
    { _Pragma("unroll") for (int q = 0; q < 8; q++) {                 \
        float fA = __shfl(vAr, (jj) * 8 + q);                         \
        float fB = __shfl(vBr, (jj) * 8 + q);                         \
        float lo = bf16_lo(buf[q]), hi = bf16_hi(buf[q]);             \
        a0A += fA * lo; a1A += fA * hi;                               \
        a0B += fB * lo; a1B += fB * hi; } }

__global__ __launch_bounds__(512) void agg_kernel(const unsigned* __restrict__ hw16,
                                                  const float* __restrict__ dis,
                                                  const int* __restrict__ rowptr,
                                                  const int2* __restrict__ csr,
                                                  const float* __restrict__ bias,
                                                  unsigned* __restrict__ out16,   // may be null
                                                  float* __restrict__ pool, int n) {
    __shared__ float lpool[128];
    int tid = threadIdx.x;
    if (tid < 128) lpool[tid] = 0.f;
    __syncthreads();

    int wave = tid >> 6, lane = tid & 63;
    int nodeA = blockIdx.x * 16 + wave * 2;
    int nodeB = nodeA + 1;
    bool okA = nodeA < n, okB = nodeB < n;

    float diA = okA ? dis[nodeA] : 0.f;
    float diB = okB ? dis[nodeB] : 0.f;
    float a0A = 0.f, a1A = 0.f, a0B = 0.f, a1B = 0.f;
    if (okA) { unsigned s = hw16[(unsigned)nodeA * 64u + lane]; a0A = diA * bf16_lo(s); a1A = diA * bf16_hi(s); }
    if (okB) { unsigned s = hw16[(unsigned)nodeB * 64u + lane]; a0B = diB * bf16_lo(s); a1B = diB * bf16_hi(s); }

    int beg = okA ? rowptr[nodeA] : 0;
    int mid = okA ? rowptr[nodeA + 1] : 0;
    int end = okB ? rowptr[nodeB + 1] : mid;

    for (int b = beg; b < end; b += 64) {
        int m = min(64, end - b);
        int sreg = 0; float vAr = 0.f, vBr = 0.f;
        if (lane < m) {
            int2 e = csr[b + lane];
            sreg = e.x;
            float v = __int_as_float(e.y);
            bool isA = (b + lane) < mid;
            vAr = isA ? v : 0.f;
            vBr = isA ? 0.f : v;
        }
        int nb = (m + 7) >> 3;
        unsigned gv0[8], gv1[8];
        AGG_ISSUE(gv0, 0)
        int j = 0;
        while (true) {
            if (j + 1 < nb) AGG_ISSUE(gv1, j + 1)
            AGG_CONSUME(gv0, j)
            j++;
            if (j >= nb) break;
            if (j + 1 < nb) AGG_ISSUE(gv0, j + 1)
            AGG_CONSUME(gv1, j)
            j++;
            if (j >= nb) break;
        }
    }

    float r0A = 0.f, r1A = 0.f, r0B = 0.f, r1B = 0.f;
    if (okA) {
        r0A = fmaxf(diA * a0A + bias[lane], 0.f);
        r1A = fmaxf(diA * a1A + bias[lane + 64], 0.f);
        if (out16) out16[(unsigned)nodeA * 64u + lane] = cvt_bf16(r0A) | (cvt_bf16(r1A) << 16);
    }
    if (okB) {
        r0B = fmaxf(diB * a0B + bias[lane], 0.f);
        r1B = fmaxf(diB * a1B + bias[lane + 64], 0.f);
        if (out16) out16[(unsigned)nodeB * 64u + lane] = cvt_bf16(r0B) | (cvt_bf16(r1B) << 16);
    }
    atomicAdd(&lpool[lane],      r0A + r0B);
    atomicAdd(&lpool[lane + 64], r1A + r1B);
    __syncthreads();
    if (tid < 128) atomicAdd(&pool[tid], lpool[tid]);
}

// ---------------- MLP head (single block) ----------------

__global__ __launch_bounds__(128) void mlp_kernel(const float* __restrict__ pool,
                                                  const float* __restrict__ fw1, const float* __restrict__ fb1,
                                                  const float* __restrict__ fw2, const float* __restrict__ fb2,
                                                  const float* __restrict__ fw3, const float* __restrict__ fb3,
                                                  float* __restrict__ out) {
    __shared__ float h0[384];
    __shared__ float h1[128];
    __shared__ float h2[64];
    int tid = threadIdx.x;
    for (int i = tid; i < 384; i += 128) h0[i] = pool[i];
    __syncthreads();
    {
        float s = fb1[tid];
        for (int k = 0; k < 384; k++) s += h0[k] * fw1[k * 128 + tid];
        h1[tid] = fmaxf(s, 0.f);
    }
    __syncthreads();
    if (tid < 64) {
        float s = fb2[tid];
        for (int k = 0; k < 128; k++) s += h1[k] * fw2[k * 64 + tid];
        h2[tid] = fmaxf(s, 0.f);
    }
    __syncthreads();
    if (tid < 10) {
        float s = fb3[tid];
        for (int k = 0; k < 64; k++) s += h2[k] * fw3[k * 10 + tid];
        out[tid] = s;
    }
}

// ---------------- launch ----------------

extern "C" void kernel_launch(void* const* d_in, const int* in_sizes, int n_in,
                              void* d_out, int out_size, void* d_ws, size_t ws_size,
                              hipStream_t stream) {
    const float* x   = (const float*)d_in[0];
    const int*   ei  = (const int*)d_in[1];
    const float* W1  = (const float*)d_in[2];
    const float* b1  = (const float*)d_in[3];
    const float* W2  = (const float*)d_in[4];
    const float* b2  = (const float*)d_in[5];
    const float* W3  = (const float*)d_in[6];
    const float* b3  = (const float*)d_in[7];
    const float* fw1 = (const float*)d_in[8];
    const float* fb1 = (const float*)d_in[9];
    const float* fw2 = (const float*)d_in[10];
    const float* fb2 = (const float*)d_in[11];
    const float* fw3 = (const float*)d_in[12];
    const float* fb3 = (const float*)d_in[13];
    float* out = (float*)d_out;

    const int n  = in_sizes[0] / FDIM;   // 50000
    const int ne = in_sizes[1] / 2;      // 600000
    const int* src = ei;
    const int* tgt = ei + ne;

    char* ws = (char*)d_ws;
    size_t packBytes = (size_t)n * 64 * sizeof(unsigned);   // 12.8 MB
    unsigned* x16  = (unsigned*)ws;  ws += packBytes;
    unsigned* hw16 = (unsigned*)ws;  ws += packBytes;
    unsigned* A2   = (unsigned*)ws;  ws += packBytes;
    unsigned* A3   = (unsigned*)ws;  ws += packBytes;
    unsigned* B1t  = (unsigned*)ws;  ws += 128 * 64 * 4;
    unsigned* B2t  = (unsigned*)ws;  ws += 128 * 64 * 4;
    unsigned* B3t  = (unsigned*)ws;  ws += 128 * 64 * 4;
    float* dis  = (float*)ws;        ws += (size_t)n * 4;
    int* count  = (int*)ws;          ws += (size_t)n * 4;
    int* rowptr = (int*)ws;          ws += ((size_t)(n + 4) * 4 / 16) * 16;
    int* cursor = (int*)ws;          ws += (size_t)n * 4;
    int2* csr   = (int2*)ws;         ws += (size_t)ne * 8;
    float* pool = (float*)ws;        ws += 384 * 4;
    int nb = (n + 2047) / 2048;      // scan blocks (25)
    int* tpre = (int*)ws;            ws += (size_t)nb * 256 * 4;
    int* bsum = (int*)ws;            ws += ((size_t)(nb + 3) / 4) * 16;
    int* bpre = (int*)ws;            ws += ((size_t)(nb + 3) / 4) * 16;

    // prep (also zeros count before hist)
    xprep_kernel<<<(n * 64 + 255) / 256, 256, 0, stream>>>(x, x16, count, n, n * 64);
    wprep_kernel<<<(3 * 8192 + 255) / 256, 256, 0, stream>>>(W1, W2, W3, B1t, B2t, B3t);

    // CSR build
    hist_kernel<<<(ne + 255) / 256, 256, 0, stream>>>(tgt, count, ne);
    scan1_kernel<<<nb, 256, 0, stream>>>(count, dis, tpre, bsum, n);
    scan2_kernel<<<1, 1024, 0, stream>>>(bsum, bpre, rowptr, pool, n, nb);
    scan3_kernel<<<nb, 256, 0, stream>>>(count, tpre, bpre, rowptr, cursor, n);
    fill_kernel<<<(ne + 255) / 256, 256, 0, stream>>>(src, tgt, dis, cursor, csr, ne);

    int gemmGrid = (n + 63) / 64;
    int aggGrid  = (n + 15) / 16;

    gemm_kernel<<<gemmGrid, 256, 0, stream>>>(x16, B1t, hw16, n);
    agg_kernel<<<aggGrid, 512, 0, stream>>>(hw16, dis, rowptr, csr, b1, A2, pool + 0, n);

    gemm_kernel<<<gemmGrid, 256, 0, stream>>>(A2, B2t, hw16, n);
    agg_kernel<<<aggGrid, 512, 0, stream>>>(hw16, dis, rowptr, csr, b2, A3, pool + 128, n);

    gemm_kernel<<<gemmGrid, 256, 0, stream>>>(A3, B3t, hw16, n);
    agg_kernel<<<aggGrid, 512, 0, stream>>>(hw16, dis, rowptr, csr, b3, (unsigned*)nullptr, pool + 256, n);

    mlp_kernel<<<1, 128, 0, stream>>>(pool, fw1, fb1, fw2, fb2, fw3, fb3, out);
}